// Round 3
// baseline (172.358 us; speedup 1.0000x reference)
//
#include <hip/hip_runtime.h>
#include <math.h>

#define BDIM 4096
#define FIN  64
#define NK   512
#define FOUT 256

#define BB    16            // batch rows per block
#define RPAD  4             // R row pad -> stride 516 (breaks bank alignment)
#define RSTR  (NK + RPAD)   // 516

__global__ __launch_bounds__(256, 1) void rbf_fused_kernel(
    const float* __restrict__ x,     // [B][FIN]
    const float* __restrict__ w,     // [FOUT][NK]
    const float* __restrict__ cent,  // [NK][FIN]
    const float* __restrict__ ls,    // [NK]
    float* __restrict__ out)         // [B][FOUT]
{
    __shared__ float xs[BB * FIN];     // 4 KB   x tile
    __shared__ float e2s[NK];          // 2 KB   exp(2*ls)
    __shared__ float invs[BB];         //        1/(1e-9+rowsum)
    __shared__ float Rs[BB * RSTR];    // 33 KB  unnormalized rbf, padded stride

    const int tid = threadIdx.x;
    const int b0  = blockIdx.x * BB;

    // ---- stage x tile (256 float4, coalesced) + exp table ----
    {
        const float4* xg = (const float4*)(x + (size_t)b0 * FIN);
        ((float4*)xs)[tid] = xg[tid];
        e2s[tid]       = __expf(2.f * ls[tid]);
        e2s[tid + 256] = __expf(2.f * ls[tid + 256]);
    }
    __syncthreads();

    // ---- phase 1: distances + rbf ----
    const int r     = tid >> 4;   // 0..15
    const int kslot = tid & 15;   // 0..15
    float4 xr[16];
    #pragma unroll
    for (int j = 0; j < 16; ++j)
        xr[j] = ((const float4*)&xs[r * FIN])[j];

    float psum = 0.f;
    #pragma unroll 2
    for (int i = 0; i < NK / 16; ++i) {
        const int k = kslot + 16 * i;
        const float4* cg = (const float4*)(cent + (size_t)k * FIN);
        float s0 = 0.f, s1 = 0.f, s2 = 0.f, s3 = 0.f;
        #pragma unroll
        for (int j = 0; j < 16; ++j) {
            float4 c4 = cg[j];
            float4 xv = xr[j];
            float d0 = xv.x - c4.x;
            float d1 = xv.y - c4.y;
            float d2 = xv.z - c4.z;
            float d3 = xv.w - c4.w;
            s0 = fmaf(d0, d0, s0);
            s1 = fmaf(d1, d1, s1);
            s2 = fmaf(d2, d2, s2);
            s3 = fmaf(d3, d3, s3);
        }
        const float ssq = (s0 + s1) + (s2 + s3);
        const float rb  = __expf(-(e2s[k] * ssq));
        Rs[r * RSTR + k] = rb;
        psum += rb;
    }
    #pragma unroll
    for (int m = 1; m < 16; m <<= 1)
        psum += __shfl_xor(psum, m, 16);
    if (kslot == 0)
        invs[r] = 1.f / (1e-9f + psum);

    __syncthreads();   // R + invs visible; no more barriers after this

    // ---- phase 2: out[16][256] = Rs * W^T, W streamed from global (L1-hot) ----
    // wave w owns cols [64w, 64w+64); lane: 4 rows x 4 consecutive cols
    const int row0 = 4 * ((tid >> 4) & 3);            // 0,4,8,12
    const int col0 = 64 * (tid >> 6) + 4 * (tid & 15);

    const float* wp0 = w + (size_t)(col0 + 0) * NK;
    const float* wp1 = w + (size_t)(col0 + 1) * NK;
    const float* wp2 = w + (size_t)(col0 + 2) * NK;
    const float* wp3 = w + (size_t)(col0 + 3) * NK;

    float acc[4][4];
    #pragma unroll
    for (int a = 0; a < 4; ++a)
        #pragma unroll
        for (int b = 0; b < 4; ++b) acc[a][b] = 0.f;

    // 1-step software pipeline: load k-step s+1 while doing fma on step s
    float4 wf[4], rf[4], wfn[4], rfn[4];
    wf[0] = *(const float4*)&wp0[0];
    wf[1] = *(const float4*)&wp1[0];
    wf[2] = *(const float4*)&wp2[0];
    wf[3] = *(const float4*)&wp3[0];
    #pragma unroll
    for (int jr = 0; jr < 4; ++jr)
        rf[jr] = *(const float4*)&Rs[(row0 + jr) * RSTR];

    #pragma unroll 2
    for (int s = 0; s < NK / 4; ++s) {
        const int kn = 4 * (s + 1);
        if (s + 1 < NK / 4) {
            wfn[0] = *(const float4*)&wp0[kn];
            wfn[1] = *(const float4*)&wp1[kn];
            wfn[2] = *(const float4*)&wp2[kn];
            wfn[3] = *(const float4*)&wp3[kn];
            #pragma unroll
            for (int jr = 0; jr < 4; ++jr)
                rfn[jr] = *(const float4*)&Rs[(row0 + jr) * RSTR + kn];
        }
        #pragma unroll
        for (int jr = 0; jr < 4; ++jr) {
            const float4 rv = rf[jr];
            #pragma unroll
            for (int jc = 0; jc < 4; ++jc) {
                const float4 wv = wf[jc];
                acc[jr][jc] = fmaf(rv.x, wv.x, acc[jr][jc]);
                acc[jr][jc] = fmaf(rv.y, wv.y, acc[jr][jc]);
                acc[jr][jc] = fmaf(rv.z, wv.z, acc[jr][jc]);
                acc[jr][jc] = fmaf(rv.w, wv.w, acc[jr][jc]);
            }
        }
        #pragma unroll
        for (int q = 0; q < 4; ++q) { wf[q] = wfn[q]; rf[q] = rfn[q]; }
    }

    // ---- epilogue: normalize + coalesced store ----
    #pragma unroll
    for (int jr = 0; jr < 4; ++jr) {
        const int row = row0 + jr;
        const float iv = invs[row];
        float4 o;
        o.x = acc[jr][0] * iv;
        o.y = acc[jr][1] * iv;
        o.z = acc[jr][2] * iv;
        o.w = acc[jr][3] * iv;
        *(float4*)(out + (size_t)(b0 + row) * FOUT + col0) = o;
    }
}

extern "C" void kernel_launch(void* const* d_in, const int* in_sizes, int n_in,
                              void* d_out, int out_size, void* d_ws, size_t ws_size,
                              hipStream_t stream) {
    const float* x    = (const float*)d_in[0];   // [4096][64]
    const float* w    = (const float*)d_in[1];   // [256][512]
    const float* cent = (const float*)d_in[2];   // [512][64]
    const float* ls   = (const float*)d_in[3];   // [512]
    float* out        = (float*)d_out;           // [4096][256]

    rbf_fused_kernel<<<dim3(BDIM / BB), dim3(256), 0, stream>>>(x, w, cent, ls, out);
}

// Round 4
// 148.721 us; speedup vs baseline: 1.1589x; 1.1589x over previous
//
#include <hip/hip_runtime.h>
#include <math.h>

#define FIN   64
#define NK    512
#define FOUT  256
#define BB    16            // batch rows per block
#define RSTR  (NK + 4)      // 516: r-stride 4 banks -> worst 2-way (free)

__device__ __forceinline__ float dot4(float4 a, float4 b, float s) {
    s = fmaf(a.x, b.x, s);
    s = fmaf(a.y, b.y, s);
    s = fmaf(a.z, b.z, s);
    s = fmaf(a.w, b.w, s);
    return s;
}

__global__ __launch_bounds__(1024, 4) void rbf_fused_kernel(
    const float* __restrict__ x,     // [B][FIN]
    const float* __restrict__ w,     // [FOUT][NK]
    const float* __restrict__ cent,  // [NK][FIN]
    const float* __restrict__ ls,    // [NK]
    float* __restrict__ out)         // [B][FOUT]
{
    __shared__ float xs[BB * FIN];   // 4 KB
    __shared__ float Rs[BB * RSTR];  // 33 KB unnormalized rbf
    __shared__ float xsq[BB];
    __shared__ float invs[BB];

    const int tid = threadIdx.x;
    const int b0  = blockIdx.x * BB;

    // ---- stage x tile: 256 float4, coalesced ----
    if (tid < 256) {
        const float4* xg = (const float4*)(x + (size_t)b0 * FIN);
        ((float4*)xs)[tid] = xg[tid];
    }
    __syncthreads();

    // ---- xsq[r]: wave r reduces row r (16 waves <-> 16 rows) ----
    {
        const int wv = tid >> 6, ln = tid & 63;
        const float v = xs[wv * FIN + ln];
        float s = v * v;
        #pragma unroll
        for (int m = 32; m >= 1; m >>= 1) s += __shfl_xor(s, m);
        if (ln == 0) xsq[wv] = s;
    }
    __syncthreads();

    // ---- phase 1: rbf via ||x||^2 - 2 x.c + ||c||^2 ----
    // lane group: jc = tid&3 covers dims [16jc,16jc+16); k = (tid>>2) + 256p
    {
        const int jc = tid & 3;
        const int kk = tid >> 2;
        #pragma unroll
        for (int p = 0; p < 2; ++p) {
            const int k = kk + 256 * p;
            const float4* cg = (const float4*)(cent + (size_t)k * FIN + 16 * jc);
            const float4 c0 = cg[0], c1 = cg[1], c2 = cg[2], c3 = cg[3];
            float csq = dot4(c3, c3, dot4(c2, c2, dot4(c1, c1, dot4(c0, c0, 0.f))));
            float cross[BB];
            #pragma unroll
            for (int r = 0; r < BB; ++r) {
                const float4* xp = (const float4*)(xs + r * FIN + 16 * jc);
                const float4 x0 = xp[0], x1 = xp[1], x2 = xp[2], x3 = xp[3];
                cross[r] = dot4(x3, c3, dot4(x2, c2, dot4(x1, c1, dot4(x0, c0, 0.f))));
            }
            // fold the 4 dim-chunks
            csq += __shfl_xor(csq, 1);
            csq += __shfl_xor(csq, 2);
            #pragma unroll
            for (int r = 0; r < BB; ++r) {
                cross[r] += __shfl_xor(cross[r], 1);
                cross[r] += __shfl_xor(cross[r], 2);
            }
            const float e2 = __expf(2.f * ls[k]);
            // lane jc writes rows jc, jc+4, jc+8, jc+12
            #pragma unroll
            for (int i = 0; i < 4; ++i) {
                const int r = jc + 4 * i;
                const float ssq = fmaf(-2.f, cross[r], xsq[r] + csq);
                Rs[r * RSTR + k] = __expf(-(e2 * ssq));
            }
        }
    }
    __syncthreads();

    // ---- row sums: wave r reduces Rs[r][:] ----
    {
        const int wv = tid >> 6, ln = tid & 63;
        const float4* rp = (const float4*)(Rs + wv * RSTR + 8 * ln);
        const float4 a = rp[0], b = rp[1];
        float s = ((a.x + a.y) + (a.z + a.w)) + ((b.x + b.y) + (b.z + b.w));
        #pragma unroll
        for (int m = 32; m >= 1; m >>= 1) s += __shfl_xor(s, m);
        if (ln == 0) invs[wv] = 1.f / (1e-9f + s);
    }
    __syncthreads();

    // ---- phase 2: out[16][256] = Rs * W^T ----
    // thread: 1 row x 4 cols. wave = 16 rows x 16 cols -> disjoint W slices.
    {
        const int row  = tid & 15;
        const int col0 = 4 * (tid >> 4);
        const float* wp0 = w + (size_t)(col0 + 0) * NK;
        const float* wp1 = w + (size_t)(col0 + 1) * NK;
        const float* wp2 = w + (size_t)(col0 + 2) * NK;
        const float* wp3 = w + (size_t)(col0 + 3) * NK;
        const float* rp  = Rs + row * RSTR;

        float a0 = 0.f, a1 = 0.f, a2 = 0.f, a3 = 0.f;
        float4 rf = *(const float4*)rp;
        float4 w0 = *(const float4*)wp0;
        float4 w1 = *(const float4*)wp1;
        float4 w2 = *(const float4*)wp2;
        float4 w3 = *(const float4*)wp3;

        #pragma unroll 4
        for (int s = 0; s < NK / 4 - 1; ++s) {
            const int kn = 4 * (s + 1);
            const float4 rfn = *(const float4*)(rp + kn);
            const float4 w0n = *(const float4*)(wp0 + kn);
            const float4 w1n = *(const float4*)(wp1 + kn);
            const float4 w2n = *(const float4*)(wp2 + kn);
            const float4 w3n = *(const float4*)(wp3 + kn);
            a0 = dot4(rf, w0, a0);
            a1 = dot4(rf, w1, a1);
            a2 = dot4(rf, w2, a2);
            a3 = dot4(rf, w3, a3);
            rf = rfn; w0 = w0n; w1 = w1n; w2 = w2n; w3 = w3n;
        }
        a0 = dot4(rf, w0, a0);
        a1 = dot4(rf, w1, a1);
        a2 = dot4(rf, w2, a2);
        a3 = dot4(rf, w3, a3);

        const float iv = invs[row];
        float4 o;
        o.x = a0 * iv;
        o.y = a1 * iv;
        o.z = a2 * iv;
        o.w = a3 * iv;
        *(float4*)(out + (size_t)(b0 + row) * FOUT + col0) = o;
    }
}

extern "C" void kernel_launch(void* const* d_in, const int* in_sizes, int n_in,
                              void* d_out, int out_size, void* d_ws, size_t ws_size,
                              hipStream_t stream) {
    const float* x    = (const float*)d_in[0];   // [4096][64]
    const float* w    = (const float*)d_in[1];   // [256][512]
    const float* cent = (const float*)d_in[2];   // [512][64]
    const float* ls   = (const float*)d_in[3];   // [512]
    float* out        = (float*)d_out;           // [4096][256]

    rbf_fused_kernel<<<dim3(4096 / BB), dim3(1024), 0, stream>>>(x, w, cent, ls, out);
}